// Round 6
// baseline (310.181 us; speedup 1.0000x reference)
//
#include <hip/hip_runtime.h>

// LightPrompt inner_structure_update (dense form), MI355X gfx950.
// Outputs (f32, concat): x[4096,128] | adj[4096,4096] | edge_attr[4096,4096,4]
// Store floor ~50us (345.6 MB @ ~6.9 TB/s). dot = tok@tok.T via f32 vector FMA
// (no fp32-input MFMA on CDNA4; bf16 MFMA rejected: mask-flip risk at the
// sigmoid threshold).
//
// R6 vs R5 (91.7us): LDS-read pipe was still critical (~61us: 12 ds_read_b128
// per wave per 4-k across 8192 waves). dot is SYMMETRIC -> compute only upper
// triangular supertiles (1056 blocks vs 2048) and write each off-diag tile
// twice: direct from registers + mirrored via an LDS d-transpose (33.8 KB,
// unioned with dead As/Bs; epilogue recomputed per mirror element, values
// bit-identical). Halves FMA (~15us) and k-loop LDS (~31us); stores (50us)
// become the critical, fire-and-forget pipe.

typedef float f32x4 __attribute__((ext_vector_type(4)));

static constexpr int Tn = 4096;
static constexpr int Dm = 128;
static constexpr int En = 4;
static constexpr float THRE = 0.55f;
static constexpr float SLOPE = 0.01f;

#define KS   32   // k split
#define LDK  36   // 32 + 4 pad (A/B tiles)
#define LDT  132  // 128 + 4 pad (d-transpose tile)
#define NSUP 32   // 4096 / 128 supertiles per dim

__host__ __device__ __forceinline__ int tri_base(int p) {
    return (p * (2 * NSUP + 1 - p)) >> 1;   // supertiles before row p (p<=q)
}

__global__ __launch_bounds__(256) void lp_fused(const float* __restrict__ tokens,
                                                const float* __restrict__ edge_token,
                                                float* __restrict__ out) {
    // union: As[128][36] (18432B) + Bs[64][36] (9216B) = 27648B  vs  dT[64][132] = 33792B
    __shared__ __align__(16) char smem[64 * LDT * 4];
    float (*As)[LDK] = reinterpret_cast<float (*)[LDK]>(smem);
    float (*Bs)[LDK] = reinterpret_cast<float (*)[LDK]>(smem + 128 * LDK * 4);
    float (*dT)[LDT] = reinterpret_cast<float (*)[LDT]>(smem);

    const int tid = threadIdx.x;
    const int bid = blockIdx.x;

    // x output = tokens verbatim: first 512 blocks, one float4 each thread.
    if (bid < 512) {
        reinterpret_cast<f32x4*>(out)[bid * 256 + tid] =
            reinterpret_cast<const f32x4*>(tokens)[bid * 256 + tid];
    }

    // Triangular supertile decode: s in [0,528) -> (p,q), p<=q. half picks the
    // 64-col j-half of the 128x128 supertile. All wave-uniform (blockIdx only).
    const int s = bid >> 1;
    const int half = bid & 1;
    int p = (int)((65.0 - sqrt(65.0 * 65.0 - 8.0 * (double)s)) * 0.5);
    if (p < 0) p = 0;
    if (p > NSUP - 1) p = NSUP - 1;
    while (p < NSUP - 1 && tri_base(p + 1) <= s) ++p;
    while (p > 0 && tri_base(p) > s) --p;
    const int q = p + (s - tri_base(p));

    const int i0 = p << 7;                    // 128 rows
    const int j0 = (q << 7) + (half << 6);    // 64 cols

    const int tx = tid & 15;   // j = j0 + tx + 16*c, c=0..3
    const int ty = tid >> 4;   // i = i0 + ty + 16*r, r=0..7

    float acc[8][4];
#pragma unroll
    for (int r = 0; r < 8; ++r)
#pragma unroll
        for (int c = 0; c < 4; ++c) acc[r][c] = 0.0f;

#pragma unroll
    for (int kp = 0; kp < Dm / KS; ++kp) {
        const int kbase = kp * KS;
        // Stage A (128x32): 1024 f32x4, 4/thread; B (64x32): 512, 2/thread.
#pragma unroll
        for (int pc = 0; pc < 4; ++pc) {
            const int f = (pc << 8) + tid;
            const int row = f >> 3;
            const int c4 = (f & 7) << 2;
            *reinterpret_cast<f32x4*>(&As[row][c4]) =
                *reinterpret_cast<const f32x4*>(tokens + (size_t)(i0 + row) * Dm + kbase + c4);
        }
#pragma unroll
        for (int pc = 0; pc < 2; ++pc) {
            const int f = (pc << 8) + tid;
            const int row = f >> 3;
            const int c4 = (f & 7) << 2;
            *reinterpret_cast<f32x4*>(&Bs[row][c4]) =
                *reinterpret_cast<const f32x4*>(tokens + (size_t)(j0 + row) * Dm + kbase + c4);
        }
        __syncthreads();

#pragma unroll
        for (int k = 0; k < KS; k += 4) {
            f32x4 b4[4];
#pragma unroll
            for (int c = 0; c < 4; ++c)
                b4[c] = *reinterpret_cast<const f32x4*>(&Bs[tx + (c << 4)][k]);
#pragma unroll
            for (int r = 0; r < 8; ++r) {
                const f32x4 a4 = *reinterpret_cast<const f32x4*>(&As[ty + (r << 4)][k]);
#pragma unroll
                for (int c = 0; c < 4; ++c)
                    acc[r][c] = fmaf(a4.x, b4[c].x,
                                fmaf(a4.y, b4[c].y,
                                fmaf(a4.z, b4[c].z,
                                fmaf(a4.w, b4[c].w, acc[r][c]))));
            }
        }
        __syncthreads();
    }

    const float e0 = edge_token[0];
    const float e1 = edge_token[1];
    const float e2 = edge_token[2];
    const float e3 = edge_token[3];

    float* __restrict__ adj  = out + (size_t)Tn * Dm;
    float* __restrict__ attr = adj + (size_t)Tn * Tn;

    const bool mirror = (p != q);

    // Stage d transposed for the mirror pass (all As/Bs reads are ordered
    // before this by the trailing k-loop barrier). dT write banks:
    // (4tx+ty+16r) mod 32 -> 2-way across a wave (free).
    if (mirror) {
#pragma unroll
        for (int r = 0; r < 8; ++r)
#pragma unroll
            for (int c = 0; c < 4; ++c)
                dT[tx + (c << 4)][ty + (r << 4)] = acc[r][c];
        __syncthreads();  // uniform branch: p,q are block-uniform
    }

    // Direct epilogue from registers.
#pragma unroll
    for (int r = 0; r < 8; ++r) {
        const int i = i0 + ty + (r << 4);
#pragma unroll
        for (int c = 0; c < 4; ++c) {
            const int j = j0 + tx + (c << 4);
            const float d = acc[r][c];
            const float sim = 1.0f / (1.0f + __expf(-d));
            const float m = (sim >= THRE) ? 1.0f : 0.0f;
            __builtin_nontemporal_store(sim * m, adj + (size_t)i * Tn + j);
            f32x4 at;
            float v;
            v = d * e0; at.x = (v > 0.0f ? v : SLOPE * v) * m;
            v = d * e1; at.y = (v > 0.0f ? v : SLOPE * v) * m;
            v = d * e2; at.z = (v > 0.0f ? v : SLOPE * v) * m;
            v = d * e3; at.w = (v > 0.0f ? v : SLOPE * v) * m;
            __builtin_nontemporal_store(at, reinterpret_cast<f32x4*>(attr + ((size_t)i * Tn + j) * En));
        }
    }

    // Mirror epilogue: rows j0+a, cols i0+b; d values bit-identical by symmetry.
    if (mirror) {
#pragma unroll
        for (int aa = 0; aa < 4; ++aa) {
            const int a = ty + (aa << 4);            // j_local 0..63
            const size_t rowbase = (size_t)(j0 + a) * Tn + i0;
#pragma unroll
            for (int bb = 0; bb < 2; ++bb) {
                const int b = (tx << 2) + (bb << 6); // i_local, 16B-aligned
                const f32x4 v = *reinterpret_cast<const f32x4*>(&dT[a][b]);
                const size_t base = rowbase + b;
                f32x4 adj4;
#pragma unroll
                for (int e = 0; e < 4; ++e) {
                    const float d = v[e];
                    const float sim = 1.0f / (1.0f + __expf(-d));
                    const float m = (sim >= THRE) ? 1.0f : 0.0f;
                    adj4[e] = sim * m;
                    f32x4 at;
                    float w;
                    w = d * e0; at.x = (w > 0.0f ? w : SLOPE * w) * m;
                    w = d * e1; at.y = (w > 0.0f ? w : SLOPE * w) * m;
                    w = d * e2; at.z = (w > 0.0f ? w : SLOPE * w) * m;
                    w = d * e3; at.w = (w > 0.0f ? w : SLOPE * w) * m;
                    __builtin_nontemporal_store(at, reinterpret_cast<f32x4*>(attr + (base + e) * 4));
                }
                __builtin_nontemporal_store(adj4, reinterpret_cast<f32x4*>(adj + base));
            }
        }
    }
}

extern "C" void kernel_launch(void* const* d_in, const int* in_sizes, int n_in,
                              void* d_out, int out_size, void* d_ws, size_t ws_size,
                              hipStream_t stream) {
    const float* tokens     = (const float*)d_in[0];  // [1,4096,128] f32
    const float* edge_token = (const float*)d_in[1];  // [1,4] f32
    float* out = (float*)d_out;

    const int nsupers = (NSUP * (NSUP + 1)) / 2;      // 528
    hipLaunchKernelGGL(lp_fused, dim3(nsupers * 2), dim3(256), 0, stream,
                       tokens, edge_token, out);
}

// Round 7
// 191.534 us; speedup vs baseline: 1.6195x; 1.6195x over previous
//
#include <hip/hip_runtime.h>

// LightPrompt inner_structure_update (dense form), MI355X gfx950.
// Outputs (f32, concat): x[4096,128] | adj[4096,4096] | edge_attr[4096,4096,4]
// Store floor ~50us (345.6 MB @ ~6.9 TB/s fill rate). dot = tok@tok.T via f32
// vector FMA (no fp32-input MFMA on CDNA4; bf16 MFMA rejected: ~9% chance of
// a mask flip at the sigmoid threshold on near-boundary diagonal dots).
//
// R7 vs R5 (91.7us): R5's critical pipe was LDS (~61us of ds_read_b128,
// barrier-locked to staging). But tokens = 2 MB -> fully L2-resident (and
// mostly L1-hot): LDS staging of cache-resident data is pure overhead
// (guide Common-mistake #7). R7 reads A/B fragments DIRECTLY from global:
// no LDS, no barriers, waves free-run, stores spread evenly. A-reads have
// 16-lane address redundancy (coalesces to 64B/instr); B-reads touch 16
// L2-hot lines/instr. Pipes: stores ~50us (critical) > VALU ~37 > VMEM ~30.
// R6 (310us) symmetry experiment reverted: halved compute but doubled
// per-block store burst on the store-floor-bound kernel + LDS-union broke
// codegen (bank conflicts 0->380K, WRITE_SIZE +65%).

typedef float f32x4 __attribute__((ext_vector_type(4)));

static constexpr int Tn = 4096;
static constexpr int Dm = 128;
static constexpr int En = 4;
static constexpr float THRE = 0.55f;
static constexpr float SLOPE = 0.01f;

#define BM 128   // block rows (i): i = i0 + ty + 16*r, r=0..7
#define BN 64    // block cols (j): j = j0 + tx + 16*c, c=0..3

__global__ __launch_bounds__(256) void lp_fused(const float* __restrict__ tokens,
                                                const float* __restrict__ edge_token,
                                                float* __restrict__ out) {
    const int tid = threadIdx.x;
    const int i0 = blockIdx.y * BM;
    const int j0 = blockIdx.x * BN;

    // x output = tokens verbatim (131072 float4): first 512 of 2048 blocks.
    const int bid = blockIdx.y * (Tn / BN) + blockIdx.x;
    if (bid < 512) {
        reinterpret_cast<f32x4*>(out)[bid * 256 + tid] =
            reinterpret_cast<const f32x4*>(tokens)[bid * 256 + tid];
    }

    const int tx = tid & 15;
    const int ty = tid >> 4;

    // Per-thread row base pointers (A rows shared by 16 lanes -> coalescer
    // merges to 4x16B per wave-instr; B rows L2/L1-resident, 16 lines/instr).
    const float* arow = tokens + (size_t)(i0 + ty) * Dm;   // + r*16*Dm
    const float* brow = tokens + (size_t)(j0 + tx) * Dm;   // + c*16*Dm

    float acc[8][4];
#pragma unroll
    for (int r = 0; r < 8; ++r)
#pragma unroll
        for (int c = 0; c < 4; ++c) acc[r][c] = 0.0f;

#pragma unroll 2
    for (int k = 0; k < Dm; k += 4) {
        f32x4 b4[4];
#pragma unroll
        for (int c = 0; c < 4; ++c)
            b4[c] = *reinterpret_cast<const f32x4*>(brow + (size_t)(c << 4) * Dm + k);
#pragma unroll
        for (int r = 0; r < 8; ++r) {
            const f32x4 a4 = *reinterpret_cast<const f32x4*>(arow + (size_t)(r << 4) * Dm + k);
#pragma unroll
            for (int c = 0; c < 4; ++c)
                acc[r][c] = fmaf(a4.x, b4[c].x,
                            fmaf(a4.y, b4[c].y,
                            fmaf(a4.z, b4[c].z,
                            fmaf(a4.w, b4[c].w, acc[r][c]))));
        }
    }

    const float e0 = edge_token[0];
    const float e1 = edge_token[1];
    const float e2 = edge_token[2];
    const float e3 = edge_token[3];

    float* __restrict__ adj  = out + (size_t)Tn * Dm;
    float* __restrict__ attr = adj + (size_t)Tn * Tn;

#pragma unroll
    for (int r = 0; r < 8; ++r) {
        const int i = i0 + ty + (r << 4);
#pragma unroll
        for (int c = 0; c < 4; ++c) {
            const int j = j0 + tx + (c << 4);
            const float d = acc[r][c];
            const float sim = 1.0f / (1.0f + __expf(-d));
            const float m = (sim >= THRE) ? 1.0f : 0.0f;
            __builtin_nontemporal_store(sim * m, adj + (size_t)i * Tn + j);
            f32x4 at;
            float v;
            v = d * e0; at.x = (v > 0.0f ? v : SLOPE * v) * m;
            v = d * e1; at.y = (v > 0.0f ? v : SLOPE * v) * m;
            v = d * e2; at.z = (v > 0.0f ? v : SLOPE * v) * m;
            v = d * e3; at.w = (v > 0.0f ? v : SLOPE * v) * m;
            __builtin_nontemporal_store(at, reinterpret_cast<f32x4*>(attr + ((size_t)i * Tn + j) * En));
        }
    }
}

extern "C" void kernel_launch(void* const* d_in, const int* in_sizes, int n_in,
                              void* d_out, int out_size, void* d_ws, size_t ws_size,
                              hipStream_t stream) {
    const float* tokens     = (const float*)d_in[0];  // [1,4096,128] f32
    const float* edge_token = (const float*)d_in[1];  // [1,4] f32
    float* out = (float*)d_out;

    hipLaunchKernelGGL(lp_fused, dim3(Tn / BN, Tn / BM), dim3(256), 0, stream,
                       tokens, edge_token, out);
}

// Round 9
// 101.147 us; speedup vs baseline: 3.0666x; 1.8936x over previous
//
#include <hip/hip_runtime.h>

// LightPrompt inner_structure_update (dense form), MI355X gfx950.
// Outputs (f32, concat): x[4096,128] | adj[4096,4096] | edge_attr[4096,4096,4]
// Store floor ~50us (345.6 MB @ ~6.9 TB/s fill rate). dot = tok@tok.T via f32
// vector FMA (no fp32-input MFMA on CDNA4; bf16 MFMA rejected: mask-flip risk
// at the sigmoid threshold).
//
// R9: back to the twice-proven both-LDS structure (R3/R5; R8's global-A +
// B-only-LDS was slower AND diverged post-timing). Critical pipe is LDS-read
// instr throughput: count/acc-elem = (R+C)/(R*C) -> 8x8 thread tile (0.25 vs
// R5's 0.375, half the waves): 2.10M ds_read_b128 -> ~41us, under the store
// floor. R4's 8x8 spill was caused by __launch_bounds__(256,4)'s 64-reg cap;
// now (256,2) -> 256-reg cap, expect ~120 VGPR, 4 waves/SIMD = LDS's 4
// blocks/CU (36.9KB). kp loop rolled to bound code size; inner k unrolled.

typedef float f32x4 __attribute__((ext_vector_type(4)));

static constexpr int Tn = 4096;
static constexpr int Dm = 128;
static constexpr int En = 4;
static constexpr float THRE = 0.55f;
static constexpr float SLOPE = 0.01f;

#define BT 128   // block tile (i and j)
#define KS 32    // k split
#define LDK 36   // 32 + 4 pad: row stride 144B; A-reads broadcast, B-reads 2-way (free)

__global__ __launch_bounds__(256, 2) void lp_fused(const float* __restrict__ tokens,
                                                   const float* __restrict__ edge_token,
                                                   float* __restrict__ out) {
    __shared__ float As[BT][LDK];
    __shared__ float Bs[BT][LDK];

    const int tid = threadIdx.x;
    const int i0 = blockIdx.y << 7;
    const int j0 = blockIdx.x << 7;

    // x output = tokens verbatim (131072 float4): first 512 of 1024 blocks.
    const int bid = blockIdx.y * (Tn / BT) + blockIdx.x;
    if (bid < 512) {
        reinterpret_cast<f32x4*>(out)[bid * 256 + tid] =
            reinterpret_cast<const f32x4*>(tokens)[bid * 256 + tid];
    }

    const int tx = tid & 15;   // j = j0 + tx + 16*c, c=0..7
    const int ty = tid >> 4;   // i = i0 + ty + 16*r, r=0..7

    float acc[8][8];
#pragma unroll
    for (int r = 0; r < 8; ++r)
#pragma unroll
        for (int c = 0; c < 8; ++c) acc[r][c] = 0.0f;

#pragma unroll 1
    for (int kp = 0; kp < Dm / KS; ++kp) {
        const int kbase = kp * KS;
        // Stage A,B (128 rows x 32 k each): 1024 f32x4 per array, 4/thread;
        // 8 threads cover one row's 128B k-slice -> coalesced.
#pragma unroll
        for (int pc = 0; pc < 4; ++pc) {
            const int f = (pc << 8) + tid;
            const int row = f >> 3;
            const int c4 = (f & 7) << 2;
            *reinterpret_cast<f32x4*>(&As[row][c4]) =
                *reinterpret_cast<const f32x4*>(tokens + (size_t)(i0 + row) * Dm + kbase + c4);
            *reinterpret_cast<f32x4*>(&Bs[row][c4]) =
                *reinterpret_cast<const f32x4*>(tokens + (size_t)(j0 + row) * Dm + kbase + c4);
        }
        __syncthreads();

        // Per wave (tx 0..15, ty 0..3): Bs 16 unique rows (2-way alias, free);
        // As 4 unique rows (16-lane broadcast). 16 ds_read_b128 per 4-k step.
#pragma unroll
        for (int k = 0; k < KS; k += 4) {
            f32x4 b4[8];
#pragma unroll
            for (int c = 0; c < 8; ++c)
                b4[c] = *reinterpret_cast<const f32x4*>(&Bs[tx + (c << 4)][k]);
#pragma unroll
            for (int r = 0; r < 8; ++r) {
                const f32x4 a4 = *reinterpret_cast<const f32x4*>(&As[ty + (r << 4)][k]);
#pragma unroll
                for (int c = 0; c < 8; ++c)
                    acc[r][c] = fmaf(a4.x, b4[c].x,
                                fmaf(a4.y, b4[c].y,
                                fmaf(a4.z, b4[c].z,
                                fmaf(a4.w, b4[c].w, acc[r][c]))));
            }
        }
        __syncthreads();
    }

    const float e0 = edge_token[0];
    const float e1 = edge_token[1];
    const float e2 = edge_token[2];
    const float e3 = edge_token[3];

    float* __restrict__ adj  = out + (size_t)Tn * Dm;
    float* __restrict__ attr = adj + (size_t)Tn * Tn;

#pragma unroll
    for (int r = 0; r < 8; ++r) {
        const int i = i0 + ty + (r << 4);
#pragma unroll
        for (int c = 0; c < 8; ++c) {
            const int j = j0 + tx + (c << 4);
            const float d = acc[r][c];
            const float sim = 1.0f / (1.0f + __expf(-d));
            const float m = (sim >= THRE) ? 1.0f : 0.0f;
            __builtin_nontemporal_store(sim * m, adj + (size_t)i * Tn + j);
            f32x4 at;
            float v;
            v = d * e0; at.x = (v > 0.0f ? v : SLOPE * v) * m;
            v = d * e1; at.y = (v > 0.0f ? v : SLOPE * v) * m;
            v = d * e2; at.z = (v > 0.0f ? v : SLOPE * v) * m;
            v = d * e3; at.w = (v > 0.0f ? v : SLOPE * v) * m;
            __builtin_nontemporal_store(at, reinterpret_cast<f32x4*>(attr + ((size_t)i * Tn + j) * En));
        }
    }
}

extern "C" void kernel_launch(void* const* d_in, const int* in_sizes, int n_in,
                              void* d_out, int out_size, void* d_ws, size_t ws_size,
                              hipStream_t stream) {
    const float* tokens     = (const float*)d_in[0];  // [1,4096,128] f32
    const float* edge_token = (const float*)d_in[1];  // [1,4] f32
    float* out = (float*)d_out;

    hipLaunchKernelGGL(lp_fused, dim3(Tn / BT, Tn / BT), dim3(256), 0, stream,
                       tokens, edge_token, out);
}

// Round 10
// 74.140 us; speedup vs baseline: 4.1837x; 1.3643x over previous
//
#include <hip/hip_runtime.h>

// LightPrompt inner_structure_update (dense form), MI355X gfx950.
// Outputs (f32, concat): x[4096,128] | adj[4096,4096] | edge_attr[4096,4096,4]
// Store floor ~50us (345.6 MB @ ~6.9 TB/s fill rate).
//
// R10: split-bf16 3-term MFMA. R5-R9 showed the VALU-f32 dot is structurally
// LDS-bound (one LDS pipe per CU serves 4 SIMDs; balance needs RC/(R+C)>=6 --
// infeasible regs). Fix: dot = ah*bh + ah*bl + al*bh with ah=bf16rn(a),
// al=bf16rn(a-ah) via mfma_f32_16x16x32_bf16; dropped al*bl term ~1e-7 abs
// (below f32-chain rounding; mask-flip risk ~0.1%). Any k-lane-mapping error
// cancels (same load pattern both operands); C/D layout is the m89-verified
// col=lane&15, row=(lane>>4)*4+reg. Compute shrinks to ~15us total ->
// store-bound. Block 128x64, 4 waves as 2x2, per wave 4x2 16x16 tiles;
// KS=32, LDS 4x[rows][40]u16 = 30KB (bank-audited: frag b128 reads and
// 8B staging writes both hit the per-bank minimum). NT stores; x-copy fused.

typedef float  f32x4  __attribute__((ext_vector_type(4)));
typedef short  bf16x8 __attribute__((ext_vector_type(8)));
typedef unsigned short u16x4 __attribute__((ext_vector_type(4)));

static constexpr int Tn = 4096;
static constexpr int Dm = 128;
static constexpr int En = 4;
static constexpr float THRE = 0.55f;
static constexpr float SLOPE = 0.01f;

#define BM 128   // block rows (i)
#define BN 64    // block cols (j)
#define KS 32    // k chunk
#define LDH 40   // u16 per LDS row: 80B stride -> conflict-free frag reads

__device__ __forceinline__ unsigned short bf16rn(float x) {
    unsigned int u = __float_as_uint(x);
    return (unsigned short)((u + 0x7FFFu + ((u >> 16) & 1u)) >> 16);
}
__device__ __forceinline__ float bf16tof(unsigned short h) {
    return __uint_as_float(((unsigned int)h) << 16);
}

__global__ __launch_bounds__(256) void lp_fused(const float* __restrict__ tokens,
                                                const float* __restrict__ edge_token,
                                                float* __restrict__ out) {
    __shared__ unsigned short Ah[BM][LDH];
    __shared__ unsigned short Al[BM][LDH];
    __shared__ unsigned short Bh[BN][LDH];
    __shared__ unsigned short Bl[BN][LDH];

    const int tid = threadIdx.x;
    const int i0 = blockIdx.y * BM;
    const int j0 = blockIdx.x * BN;

    // x output = tokens verbatim (131072 float4): first 512 of 2048 blocks.
    const int bid = blockIdx.y * (Tn / BN) + blockIdx.x;
    if (bid < 512) {
        reinterpret_cast<f32x4*>(out)[bid * 256 + tid] =
            reinterpret_cast<const f32x4*>(tokens)[bid * 256 + tid];
    }

    const int lane = tid & 63;
    const int w    = tid >> 6;   // wave 0..3
    const int wr   = w >> 1;     // row half (64 rows)
    const int wc   = w & 1;      // col half (32 cols)
    const int lr   = lane & 15;  // frag row/col within 16x16 tile
    const int lk   = lane >> 4;  // k quarter (8 bf16 each)

    f32x4 acc[4][2];
#pragma unroll
    for (int rt = 0; rt < 4; ++rt)
#pragma unroll
        for (int ct = 0; ct < 2; ++ct) acc[rt][ct] = (f32x4)(0.0f);

#pragma unroll 1
    for (int kp = 0; kp < Dm / KS; ++kp) {
        const int kbase = kp * KS;
        // Stage A (128x32 f32 -> hi/lo bf16): 4 f32x4/thread, 8 lanes per row.
#pragma unroll
        for (int p = 0; p < 4; ++p) {
            const int f = (p << 8) + tid;        // 0..1023
            const int row = f >> 3;
            const int c4 = (f & 7) << 2;
            const f32x4 v = *reinterpret_cast<const f32x4*>(
                tokens + (size_t)(i0 + row) * Dm + kbase + c4);
            u16x4 hi, lo;
#pragma unroll
            for (int e = 0; e < 4; ++e) {
                const unsigned short h = bf16rn(v[e]);
                hi[e] = h;
                lo[e] = bf16rn(v[e] - bf16tof(h));
            }
            *reinterpret_cast<u16x4*>(&Ah[row][c4]) = hi;
            *reinterpret_cast<u16x4*>(&Al[row][c4]) = lo;
        }
        // Stage B (64x32): 2 f32x4/thread.
#pragma unroll
        for (int p = 0; p < 2; ++p) {
            const int f = (p << 8) + tid;        // 0..511
            const int row = f >> 3;
            const int c4 = (f & 7) << 2;
            const f32x4 v = *reinterpret_cast<const f32x4*>(
                tokens + (size_t)(j0 + row) * Dm + kbase + c4);
            u16x4 hi, lo;
#pragma unroll
            for (int e = 0; e < 4; ++e) {
                const unsigned short h = bf16rn(v[e]);
                hi[e] = h;
                lo[e] = bf16rn(v[e] - bf16tof(h));
            }
            *reinterpret_cast<u16x4*>(&Bh[row][c4]) = hi;
            *reinterpret_cast<u16x4*>(&Bl[row][c4]) = lo;
        }
        __syncthreads();

        // Fragments: lane lr = tile row/col, lk*8 = k offset (16B b128 reads).
        bf16x8 afh[4], afl[4], bfh[2], bfl[2];
#pragma unroll
        for (int rt = 0; rt < 4; ++rt) {
            const int row = (wr << 6) + (rt << 4) + lr;
            afh[rt] = *reinterpret_cast<const bf16x8*>(&Ah[row][lk << 3]);
            afl[rt] = *reinterpret_cast<const bf16x8*>(&Al[row][lk << 3]);
        }
#pragma unroll
        for (int ct = 0; ct < 2; ++ct) {
            const int col = (wc << 5) + (ct << 4) + lr;
            bfh[ct] = *reinterpret_cast<const bf16x8*>(&Bh[col][lk << 3]);
            bfl[ct] = *reinterpret_cast<const bf16x8*>(&Bl[col][lk << 3]);
        }
#pragma unroll
        for (int rt = 0; rt < 4; ++rt)
#pragma unroll
            for (int ct = 0; ct < 2; ++ct) {
                acc[rt][ct] = __builtin_amdgcn_mfma_f32_16x16x32_bf16(
                    afh[rt], bfh[ct], acc[rt][ct], 0, 0, 0);
                acc[rt][ct] = __builtin_amdgcn_mfma_f32_16x16x32_bf16(
                    afh[rt], bfl[ct], acc[rt][ct], 0, 0, 0);
                acc[rt][ct] = __builtin_amdgcn_mfma_f32_16x16x32_bf16(
                    afl[rt], bfh[ct], acc[rt][ct], 0, 0, 0);
            }
        __syncthreads();
    }

    const float e0 = edge_token[0];
    const float e1 = edge_token[1];
    const float e2 = edge_token[2];
    const float e3 = edge_token[3];

    float* __restrict__ adj  = out + (size_t)Tn * Dm;
    float* __restrict__ attr = adj + (size_t)Tn * Tn;

    // C/D layout (m89-verified): col = lane&15, row = (lane>>4)*4 + reg.
#pragma unroll
    for (int rt = 0; rt < 4; ++rt) {
#pragma unroll
        for (int ct = 0; ct < 2; ++ct) {
            const f32x4 dv = acc[rt][ct];
            const int j = j0 + (wc << 5) + (ct << 4) + lr;
#pragma unroll
            for (int reg = 0; reg < 4; ++reg) {
                const int i = i0 + (wr << 6) + (rt << 4) + (lk << 2) + reg;
                const float d = dv[reg];
                const float sim = 1.0f / (1.0f + __expf(-d));
                const float m = (sim >= THRE) ? 1.0f : 0.0f;
                __builtin_nontemporal_store(sim * m, adj + (size_t)i * Tn + j);
                f32x4 at;
                float v;
                v = d * e0; at.x = (v > 0.0f ? v : SLOPE * v) * m;
                v = d * e1; at.y = (v > 0.0f ? v : SLOPE * v) * m;
                v = d * e2; at.z = (v > 0.0f ? v : SLOPE * v) * m;
                v = d * e3; at.w = (v > 0.0f ? v : SLOPE * v) * m;
                __builtin_nontemporal_store(at,
                    reinterpret_cast<f32x4*>(attr + ((size_t)i * Tn + j) * En));
            }
        }
    }
}

extern "C" void kernel_launch(void* const* d_in, const int* in_sizes, int n_in,
                              void* d_out, int out_size, void* d_ws, size_t ws_size,
                              hipStream_t stream) {
    const float* tokens     = (const float*)d_in[0];  // [1,4096,128] f32
    const float* edge_token = (const float*)d_in[1];  // [1,4] f32
    float* out = (float*)d_out;

    hipLaunchKernelGGL(lp_fused, dim3(Tn / BN, Tn / BM), dim3(256), 0, stream,
                       tokens, edge_token, out);
}